// Round 1
// baseline (220.078 us; speedup 1.0000x reference)
//
#include <hip/hip_runtime.h>

// PatchEncoder fused kernel.
// Algebra: patch(4)/+pos/unpatch/patch(16) collapse to a pure index permutation:
//   out[b, (h/16)*32 + w/16, (h%16)*48 + (w%16)*3 + c]
//     = conv3x3_SAME(X)[b,h,w,c] + bias[c]
//       + pos_emb[(h/4)*128 + (w/4), (h%4)*12 + (w%4)*3 + c]
// B=32, H=W=512, C=3. out: [32, 1024, 768] fp32.

#define BATCH 32
#define IMH 512
#define IMW 512
#define TH 16      // tile rows  = one coarse patch row
#define TW 64      // tile cols  = 4 coarse patches -> 3072 contiguous out floats
#define RS 68      // LDS row stride (floats); 68*4 = 272 B = 17*16B -> float4-aligned rows
#define PLANE (18 * RS)   // one channel plane: 18 halo rows

__global__ __launch_bounds__(256) void patch_enc_kernel(
    const float* __restrict__ X,     // [B,H,W,3] NHWC
    const float* __restrict__ Kw,    // [3,3,3,3] HWIO
    const float* __restrict__ bias,  // [3]
    const float* __restrict__ pos,   // [16384,48]
    float* __restrict__ out)         // [B,1024,768]
{
    __shared__ float lds[3 * PLANE];  // SoA channel planes, 14.7 KB

    const int tid = threadIdx.x;
    const int w0 = blockIdx.x * TW;   // 0..448
    const int h0 = blockIdx.y * TH;   // 0..496
    const int b  = blockIdx.z;

    // ---- stage halo tile (rows h0-1..h0+16, cols w0-1..w0+64) into 3 planes ----
    // LDS col index L <-> global w = w0 - 1 + L ; row index R <-> h = h0 - 1 + R
    const float* Xb = X + (size_t)b * IMH * IMW * 3;
    for (int idx = tid; idx < 18 * 198; idx += 256) {
        int row = idx / 198;
        int e   = idx - row * 198;      // 0..197, consecutive lanes -> consecutive gmem
        int col = e / 3;                // 0..65
        int ch  = e - col * 3;
        int h = h0 - 1 + row;
        int w = w0 - 1 + col;
        float v = 0.0f;                 // SAME zero padding
        if ((unsigned)h < IMH && (unsigned)w < IMW)
            v = Xb[((size_t)h * IMW + w) * 3 + ch];
        lds[ch * PLANE + row * RS + col] = v;
    }

    // weights: uniform indices -> scalar loads -> SGPR operands for v_fmac
    float wk[81];
#pragma unroll
    for (int i = 0; i < 81; ++i) wk[i] = Kw[i];
    const float bs0 = bias[0], bs1 = bias[1], bs2 = bias[2];

    __syncthreads();

    // ---- each thread: 4 horizontal pixels (row r, cols c0..c0+3) ----
    const int r  = tid & 15;    // lane%16 -> fast dim for LDS bank spread
    const int g  = tid >> 4;    // column group 0..15
    const int c0 = g << 2;

    float acc[12];              // [pixel i][outch oc] flattened i*3+oc
#pragma unroll
    for (int i = 0; i < 12; ++i) acc[i] = 0.0f;

#pragma unroll
    for (int dr = 0; dr < 3; ++dr) {
#pragma unroll
        for (int ci = 0; ci < 3; ++ci) {
            // window cols (global) w0+c0-1 .. w0+c0+4 -> LDS cols c0..c0+5
            const float* bp = &lds[ci * PLANE + (r + dr) * RS + c0]; // 16B aligned
            const float4 a4 = *(const float4*)bp;
            const float2 a2 = *(const float2*)(bp + 4);
            const float rv[6] = {a4.x, a4.y, a4.z, a4.w, a2.x, a2.y};
#pragma unroll
            for (int dc = 0; dc < 3; ++dc) {
                const float* wp = &wk[((dr * 3 + dc) * 3 + ci) * 3];
#pragma unroll
                for (int i = 0; i < 4; ++i) {
                    const float x = rv[i + dc];
                    acc[i * 3 + 0] = fmaf(x, wp[0], acc[i * 3 + 0]);
                    acc[i * 3 + 1] = fmaf(x, wp[1], acc[i * 3 + 1]);
                    acc[i * 3 + 2] = fmaf(x, wp[2], acc[i * 3 + 2]);
                }
            }
        }
    }

    // ---- epilogue: bias + pos_emb (12 consecutive floats) + permuted store ----
    const int hg = h0 + r;
    // fine patch n; 4 pixels (w&3 = 0..3) + 3 ch = 12 consecutive pos floats
    const int n = (hg >> 2) * 128 + (w0 >> 2) + g;
    const float* pp = pos + (size_t)n * 48 + (hg & 3) * 12;  // 48B aligned
    const float4 p0 = ((const float4*)pp)[0];
    const float4 p1 = ((const float4*)pp)[1];
    const float4 p2 = ((const float4*)pp)[2];

    float v[12];
    v[0]  = acc[0]  + bs0 + p0.x;  v[1]  = acc[1]  + bs1 + p0.y;
    v[2]  = acc[2]  + bs2 + p0.z;  v[3]  = acc[3]  + bs0 + p0.w;
    v[4]  = acc[4]  + bs1 + p1.x;  v[5]  = acc[5]  + bs2 + p1.y;
    v[6]  = acc[6]  + bs0 + p1.z;  v[7]  = acc[7]  + bs1 + p1.w;
    v[8]  = acc[8]  + bs2 + p2.x;  v[9]  = acc[9]  + bs0 + p2.y;
    v[10] = acc[10] + bs1 + p2.z;  v[11] = acc[11] + bs2 + p2.w;

    // out[b, np, r*48 + (g&3)*12 .. +11] — 12 consecutive floats, 48B aligned
    const int np = (h0 >> 4) * 32 + (w0 >> 4) + (g >> 2);
    float* op = out + (size_t)b * 786432 + (size_t)np * 768 + r * 48 + (g & 3) * 12;
    ((float4*)op)[0] = make_float4(v[0], v[1], v[2],  v[3]);
    ((float4*)op)[1] = make_float4(v[4], v[5], v[6],  v[7]);
    ((float4*)op)[2] = make_float4(v[8], v[9], v[10], v[11]);
}

extern "C" void kernel_launch(void* const* d_in, const int* in_sizes, int n_in,
                              void* d_out, int out_size, void* d_ws, size_t ws_size,
                              hipStream_t stream) {
    const float* X    = (const float*)d_in[0];
    const float* Kw   = (const float*)d_in[1];
    const float* bias = (const float*)d_in[2];
    const float* pos  = (const float*)d_in[3];
    float* out = (float*)d_out;

    dim3 grid(IMW / TW, IMH / TH, BATCH);   // 8 x 32 x 32 = 8192 blocks
    patch_enc_kernel<<<grid, 256, 0, stream>>>(X, Kw, bias, pos, out);
}

// Round 2
// 213.017 us; speedup vs baseline: 1.0332x; 1.0332x over previous
//
#include <hip/hip_runtime.h>

// PatchEncoder fused kernel, round 2.
// out[b, (h/16)*32 + w/16, (h%16)*48 + (w%16)*3 + c]
//   = conv3x3_SAME(X)[b,h,w,c] + bias[c]
//     + pos_emb[(h/4)*128 + (w/4), (h%4)*12 + (w%4)*3 + c]
// B=32, H=W=512, C=3. out: [32, 1024, 768] fp32.
//
// R2 changes vs R1 (96 us, latency-bound: VGPR=32, all pipes <35%):
//  - 32x64 tile, each thread computes a 2-row x 4-col pixel block (8 px):
//    12 row-segments feed 8 px -> 3 LDS read inst/px (was 4.5).
//  - per-channel register batching: issue all 8 ds_reads, then 216 FMAs.
//  - staging: one dwordx3 per pixel (12B, 4B-aligned), uniform
//    interior/edge branch instead of per-element bounds checks.

#define BATCH 32
#define IMH 512
#define IMW 512
#define TH 32      // tile rows
#define TW 64      // tile cols
#define HR 34      // halo rows
#define HC 66      // halo cols
#define RS 68      // LDS row stride (floats); 272 B = 17*16B -> float4-aligned
#define PLANE (HR * RS)   // 2312 floats per channel plane; 3 planes = 27.7 KB

__global__ __launch_bounds__(256) void patch_enc_kernel(
    const float* __restrict__ X,     // [B,H,W,3] NHWC
    const float* __restrict__ Kw,    // [3,3,3,3] HWIO
    const float* __restrict__ bias,  // [3]
    const float* __restrict__ pos,   // [16384,48]
    float* __restrict__ out)         // [B,1024,768]
{
    __shared__ float lds[3 * PLANE];

    const int tid = threadIdx.x;
    const int w0 = blockIdx.x * TW;   // 0..448
    const int h0 = blockIdx.y * TH;   // 0..480
    const int b  = blockIdx.z;

    const float* Xb = X + (size_t)b * IMH * IMW * 3;

    // ---- stage halo (rows h0-1..h0+32, cols w0-1..w0+64), SoA channel planes ----
    if (h0 > 0 && h0 + TH + 1 <= IMH && w0 > 0 && w0 + TW + 1 <= IMW) {
        // interior: no bounds checks
        for (int idx = tid; idx < HR * HC; idx += 256) {
            int row = idx / HC;
            int col = idx - row * HC;
            const float* p = Xb + ((size_t)(h0 - 1 + row) * IMW + (w0 - 1 + col)) * 3;
            float a0 = p[0], a1 = p[1], a2 = p[2];   // -> global_load_dwordx3
            int lo = row * RS + col;
            lds[lo] = a0; lds[PLANE + lo] = a1; lds[2 * PLANE + lo] = a2;
        }
    } else {
        for (int idx = tid; idx < HR * HC; idx += 256) {
            int row = idx / HC;
            int col = idx - row * HC;
            int h = h0 - 1 + row;
            int w = w0 - 1 + col;
            float a0 = 0.f, a1 = 0.f, a2 = 0.f;
            if ((unsigned)h < IMH && (unsigned)w < IMW) {
                const float* p = Xb + ((size_t)h * IMW + w) * 3;
                a0 = p[0]; a1 = p[1]; a2 = p[2];
            }
            int lo = row * RS + col;
            lds[lo] = a0; lds[PLANE + lo] = a1; lds[2 * PLANE + lo] = a2;
        }
    }

    // weights: uniform -> scalar loads -> SGPRs
    float wk[81];
#pragma unroll
    for (int i = 0; i < 81; ++i) wk[i] = Kw[i];
    const float bs[3] = {bias[0], bias[1], bias[2]};

    __syncthreads();

    // ---- compute: thread -> rows 2*rp, 2*rp+1 ; cols c0..c0+3 ----
    const int rp = tid & 15;    // row pair 0..15
    const int g  = tid >> 4;    // col group 0..15
    const int c0 = g << 2;

    float acc[2][12];
#pragma unroll
    for (int e = 0; e < 2; ++e)
#pragma unroll
        for (int i = 0; i < 12; ++i) acc[e][i] = 0.0f;

#pragma unroll
    for (int ch = 0; ch < 3; ++ch) {
        // batch all 4 halo rows (2*rp .. 2*rp+3) of this channel: 8 ds_reads in flight
        float s[4][6];
#pragma unroll
        for (int k = 0; k < 4; ++k) {
            const float* bp = &lds[ch * PLANE + (2 * rp + k) * RS + c0]; // 16B aligned
            const float4 a4 = *(const float4*)bp;
            const float2 a2 = *(const float2*)(bp + 4);
            s[k][0] = a4.x; s[k][1] = a4.y; s[k][2] = a4.z;
            s[k][3] = a4.w; s[k][4] = a2.x; s[k][5] = a2.y;
        }
#pragma unroll
        for (int e = 0; e < 2; ++e)
#pragma unroll
            for (int dr = 0; dr < 3; ++dr)
#pragma unroll
                for (int dc = 0; dc < 3; ++dc) {
                    const float* wp = &wk[((dr * 3 + dc) * 3 + ch) * 3];
#pragma unroll
                    for (int i = 0; i < 4; ++i) {
                        const float x = s[e + dr][i + dc];
                        acc[e][i * 3 + 0] = fmaf(x, wp[0], acc[e][i * 3 + 0]);
                        acc[e][i * 3 + 1] = fmaf(x, wp[1], acc[e][i * 3 + 1]);
                        acc[e][i * 3 + 2] = fmaf(x, wp[2], acc[e][i * 3 + 2]);
                    }
                }
    }

    // ---- epilogue: bias + pos_emb + permuted store, per row of the pair ----
#pragma unroll
    for (int e = 0; e < 2; ++e) {
        const int hg = h0 + 2 * rp + e;          // global row
        const int wg = w0 + c0;                  // global col of px 0
        const int n  = (hg >> 2) * 128 + (wg >> 2);
        const float* pp = pos + (size_t)n * 48 + (hg & 3) * 12;   // 48B aligned
        const float4 p0 = ((const float4*)pp)[0];
        const float4 p1 = ((const float4*)pp)[1];
        const float4 p2 = ((const float4*)pp)[2];

        float v[12];
        v[0]  = acc[e][0]  + bs[0] + p0.x;  v[1]  = acc[e][1]  + bs[1] + p0.y;
        v[2]  = acc[e][2]  + bs[2] + p0.z;  v[3]  = acc[e][3]  + bs[0] + p0.w;
        v[4]  = acc[e][4]  + bs[1] + p1.x;  v[5]  = acc[e][5]  + bs[2] + p1.y;
        v[6]  = acc[e][6]  + bs[0] + p1.z;  v[7]  = acc[e][7]  + bs[1] + p1.w;
        v[8]  = acc[e][8]  + bs[2] + p2.x;  v[9]  = acc[e][9]  + bs[0] + p2.y;
        v[10] = acc[e][10] + bs[1] + p2.z;  v[11] = acc[e][11] + bs[2] + p2.w;

        const int np = (hg >> 4) * 32 + (wg >> 4);
        float* op = out + (size_t)b * 786432 + (size_t)np * 768
                        + (hg & 15) * 48 + ((wg & 15) >> 2) * 12;
        ((float4*)op)[0] = make_float4(v[0], v[1], v[2],  v[3]);
        ((float4*)op)[1] = make_float4(v[4], v[5], v[6],  v[7]);
        ((float4*)op)[2] = make_float4(v[8], v[9], v[10], v[11]);
    }
}

extern "C" void kernel_launch(void* const* d_in, const int* in_sizes, int n_in,
                              void* d_out, int out_size, void* d_ws, size_t ws_size,
                              hipStream_t stream) {
    const float* X    = (const float*)d_in[0];
    const float* Kw   = (const float*)d_in[1];
    const float* bias = (const float*)d_in[2];
    const float* pos  = (const float*)d_in[3];
    float* out = (float*)d_out;

    dim3 grid(IMW / TW, IMH / TH, BATCH);   // 8 x 16 x 32 = 4096 blocks
    patch_enc_kernel<<<grid, 256, 0, stream>>>(X, Kw, bias, pos, out);
}

// Round 3
// 206.222 us; speedup vs baseline: 1.0672x; 1.0329x over previous
//
#include <hip/hip_runtime.h>

// PatchEncoder fused kernel, round 3.
// out[b, (h/16)*32 + w/16, (h%16)*48 + (w%16)*3 + c]
//   = conv3x3_SAME(X)[b,h,w,c] + bias[c]
//     + pos_emb[(h/4)*128 + (w/4), (h%4)*12 + (w%4)*3 + c]
// B=32, H=W=512, C=3. out: [32, 1024, 768] fp32.
//
// R3: drop LDS entirely (R1/R2 were latency-bound on the serialized staging
// loop + barrier drain + b64 bank conflicts; intra-block reuse is only ~2.7x
// and fits L1). Each thread loads a private 4-row x 20-float 16B-aligned
// window (20 independent dwordx4, one latency exposure), 648 reg FMAs, done.
// Lane map g-fast: 16 consecutive lanes span ~800B contiguous per row load.

#define BATCH 32
#define IMH 512
#define IMW 512

__global__ __launch_bounds__(256) void patch_enc_kernel(
    const float* __restrict__ X,     // [B,H,W,3] NHWC
    const float* __restrict__ Kw,    // [3,3,3,3] HWIO
    const float* __restrict__ bias,  // [3]
    const float* __restrict__ pos,   // [16384,48]
    float* __restrict__ out)         // [B,1024,768]
{
    const int tid = threadIdx.x;
    const int g   = tid & 15;        // column group (fast -> coalesced loads)
    const int rp  = tid >> 4;        // row pair
    const int w0  = blockIdx.x * 64;
    const int h0  = blockIdx.y * 32;
    const int b   = blockIdx.z;

    const int wg0 = w0 + (g << 2);   // first output col of this thread
    const int hb  = h0 + (rp << 1);  // first output row of this thread

    const float* Xb = X + (size_t)b * (IMH * IMW * 3);

    // weights: uniform indices -> s_load -> SGPR operands
    float wk[81];
#pragma unroll
    for (int i = 0; i < 81; ++i) wk[i] = Kw[i];
    const float bs[3] = {bias[0], bias[1], bias[2]};

    // ---- load 4 input rows x 20 floats (cols wg0-1..wg0+4, NHWC interleaved)
    // row window floats [3*wg0-4, 3*wg0+16): 16B aligned (3*wg0 % 4 == 0).
    // used: j = 3*(i+dc) + ci + 1, i.e. j in [1,18].
    const bool notL = (wg0 != 0);          // left image edge: zero j=1..3
    const bool notR = (wg0 != IMW - 4);    // right image edge: zero j=16..18
    float win[4][20];
#pragma unroll
    for (int k = 0; k < 4; ++k) {
        const int h = hb - 1 + k;
        if ((unsigned)h < IMH) {
            const float* rowp = Xb + (size_t)h * (IMW * 3) + 3 * wg0 - 4;
            if (notL) {
                *(float4*)&win[k][0] = *(const float4*)rowp;
            } else {
                win[k][0] = 0.f; win[k][1] = 0.f; win[k][2] = 0.f; win[k][3] = 0.f;
            }
            *(float4*)&win[k][4]  = *(const float4*)(rowp + 4);
            *(float4*)&win[k][8]  = *(const float4*)(rowp + 8);
            *(float4*)&win[k][12] = *(const float4*)(rowp + 12);
            if (notR) {
                *(float4*)&win[k][16] = *(const float4*)(rowp + 16);
            } else {
                win[k][16] = 0.f; win[k][17] = 0.f; win[k][18] = 0.f; win[k][19] = 0.f;
            }
        } else {
#pragma unroll
            for (int j = 0; j < 20; ++j) win[k][j] = 0.f;
        }
    }

    // ---- conv: 2 output rows x 4 cols x 3 outch, all operands in regs ----
    float acc[2][12];
#pragma unroll
    for (int e = 0; e < 2; ++e)
#pragma unroll
        for (int i = 0; i < 12; ++i) acc[e][i] = 0.0f;

#pragma unroll
    for (int e = 0; e < 2; ++e)
#pragma unroll
        for (int dr = 0; dr < 3; ++dr) {
            const float* s = win[e + dr];   // input row hb+e+dr-1
#pragma unroll
            for (int dc = 0; dc < 3; ++dc)
#pragma unroll
                for (int ci = 0; ci < 3; ++ci) {
                    const float* wp = &wk[((dr * 3 + dc) * 3 + ci) * 3];
#pragma unroll
                    for (int i = 0; i < 4; ++i) {
                        const float x = s[3 * (i + dc) + ci + 1];
                        acc[e][i * 3 + 0] = fmaf(x, wp[0], acc[e][i * 3 + 0]);
                        acc[e][i * 3 + 1] = fmaf(x, wp[1], acc[e][i * 3 + 1]);
                        acc[e][i * 3 + 2] = fmaf(x, wp[2], acc[e][i * 3 + 2]);
                    }
                }
        }

    // ---- epilogue: bias + pos_emb + permuted store, per output row ----
#pragma unroll
    for (int e = 0; e < 2; ++e) {
        const int hg = hb + e;
        const int n  = (hg >> 2) * 128 + (wg0 >> 2);
        const float* pp = pos + (size_t)n * 48 + (hg & 3) * 12;   // 48B aligned
        const float4 p0 = ((const float4*)pp)[0];
        const float4 p1 = ((const float4*)pp)[1];
        const float4 p2 = ((const float4*)pp)[2];

        float v[12];
        v[0]  = acc[e][0]  + bs[0] + p0.x;  v[1]  = acc[e][1]  + bs[1] + p0.y;
        v[2]  = acc[e][2]  + bs[2] + p0.z;  v[3]  = acc[e][3]  + bs[0] + p0.w;
        v[4]  = acc[e][4]  + bs[1] + p1.x;  v[5]  = acc[e][5]  + bs[2] + p1.y;
        v[6]  = acc[e][6]  + bs[0] + p1.z;  v[7]  = acc[e][7]  + bs[1] + p1.w;
        v[8]  = acc[e][8]  + bs[2] + p2.x;  v[9]  = acc[e][9]  + bs[0] + p2.y;
        v[10] = acc[e][10] + bs[1] + p2.z;  v[11] = acc[e][11] + bs[2] + p2.w;

        const int np = (hg >> 4) * 32 + (wg0 >> 4);
        float* op = out + (size_t)b * 786432 + (size_t)np * 768
                        + (hg & 15) * 48 + ((wg0 & 15) >> 2) * 12;
        ((float4*)op)[0] = make_float4(v[0], v[1], v[2],  v[3]);
        ((float4*)op)[1] = make_float4(v[4], v[5], v[6],  v[7]);
        ((float4*)op)[2] = make_float4(v[8], v[9], v[10], v[11]);
    }
}

extern "C" void kernel_launch(void* const* d_in, const int* in_sizes, int n_in,
                              void* d_out, int out_size, void* d_ws, size_t ws_size,
                              hipStream_t stream) {
    const float* X    = (const float*)d_in[0];
    const float* Kw   = (const float*)d_in[1];
    const float* bias = (const float*)d_in[2];
    const float* pos  = (const float*)d_in[3];
    float* out = (float*)d_out;

    dim3 grid(IMW / 64, IMH / 32, BATCH);   // 8 x 16 x 32 = 4096 blocks
    patch_enc_kernel<<<grid, 256, 0, stream>>>(X, Kw, bias, pos, out);
}

// Round 4
// 192.854 us; speedup vs baseline: 1.1412x; 1.0693x over previous
//
#include <hip/hip_runtime.h>

// PatchEncoder fused kernel, round 4.
// out[b, (h/16)*32 + w/16, (h%16)*48 + (w%16)*3 + c]
//   = conv3x3_SAME(X)[b,h,w,c] + bias[c]
//     + pos_emb[(h/4)*128 + (w/4), (h%4)*12 + (w%4)*3 + c]
//
// R1-R3 were all latency-bound (every pipe <30%): the compiler serializes
// register staging through a small VGPR window no matter how the source
// batches it. R4 uses async DMA global_load_lds (no dest VGPRs -> nothing
// to serialize): <=5 DMA insts/wave all in flight, one barrier drain, then
// compute from LDS via ds_read_b128 at the conflict-free floor.
//
// LDS layout: 18 halo rows as raw NHWC row slices. Row r origin = global
// float (h*1536 + 3*w0 - 4) (16B-aligned: 1536*4 and 64*12 are mult of 16).
// Row stride 260 floats (1040 B = 65*16): ds_read_b128 lane bank residue
// (4r + 12g) mod 32 -> r+3g mod 8 uniform over 64 lanes -> zero conflicts.

#define BATCH 32
#define IMH 512
#define IMW 512
#define RSF 260            // LDS row stride, floats
#define NROW 18

__device__ __forceinline__ void dma16(const float* g, float* l) {
    __builtin_amdgcn_global_load_lds(
        (const __attribute__((address_space(1))) void*)g,
        (__attribute__((address_space(3))) void*)l,
        16, 0, 0);
}

__global__ __launch_bounds__(256, 6) void patch_enc_kernel(
    const float* __restrict__ X,     // [B,H,W,3] NHWC
    const float* __restrict__ Kw,    // [3,3,3,3] HWIO
    const float* __restrict__ bias,  // [3]
    const float* __restrict__ pos,   // [16384,48]
    float* __restrict__ out)         // [B,1024,768]
{
    __shared__ float lds[NROW * RSF];   // 18.7 KB

    const int tid = threadIdx.x;
    const int w0  = blockIdx.x * 64;
    const int h0  = blockIdx.y * 16;
    const int b   = blockIdx.z;

    const bool lEdge = (w0 == 0);
    const bool rEdge = (w0 == IMW - 64);
    const bool tEdge = (h0 == 0);
    const bool bEdge = (h0 == IMH - 16);

    const float* Xb = X + (size_t)b * (IMH * IMW * 3);

    // ---- async-stage 18 halo rows: one global_load_lds(16B) per row/wave ----
    // lane i writes LDS bytes [row*1040 + i*16, +16) from gp = rowbase + i*16.
    {
        const int lane = tid & 63;
        const int wv   = tid >> 6;
        const float* xlo = X;                                      // clamp lo (b=0 top-left)
        const float* xhi = X + (size_t)BATCH * IMH * IMW * 3 - 4;  // clamp hi (last 16B start)
        for (int row = wv; row < NROW; row += 4) {
            const int h = h0 - 1 + row;
            if ((unsigned)h < IMH) {                // wave-uniform branch
                const float* gp = Xb + (size_t)h * (IMW * 3) + (3 * w0 - 4) + lane * 4;
                if (lEdge) gp = (gp < xlo) ? xlo : gp;   // cndmask, exec stays full
                if (rEdge) gp = (gp > xhi) ? xhi : gp;
                dma16(gp, &lds[row * RSF]);
            }
        }
    }

    // weights while DMA is in flight: uniform -> s_load -> SGPR operands
    float wk[81];
#pragma unroll
    for (int i = 0; i < 81; ++i) wk[i] = Kw[i];
    const float bs[3] = {bias[0], bias[1], bias[2]};

    __syncthreads();   // drains vmcnt: all DMA rows landed

    // ---- zero-pad fixups (edge blocks only; cells were DMA'd with garbage) ----
    if (tEdge) for (int j = tid; j < RSF; j += 256) lds[j] = 0.0f;                // row h=-1
    if (bEdge) for (int j = tid; j < RSF; j += 256) lds[(NROW - 1) * RSF + j] = 0.0f; // h=512
    if (lEdge && tid < 72) lds[(tid >> 2) * RSF + (tid & 3)] = 0.0f;              // col -1
    if (rEdge && tid < 72) lds[(tid >> 2) * RSF + 196 + (tid & 3)] = 0.0f;        // col 512
    __syncthreads();

    // ---- compute: thread -> output row r (16), col group g (16) ----
    const int g = tid & 15;
    const int r = tid >> 4;

    float acc[12];
#pragma unroll
    for (int i = 0; i < 12; ++i) acc[i] = 0.0f;

#pragma unroll
    for (int dr = 0; dr < 3; ++dr) {
        // input row h0-1+r+dr = LDS row r+dr; floats 12g..12g+19 (need 1..18)
        const float* bp = &lds[(r + dr) * RSF + 12 * g];
        float s[20];
#pragma unroll
        for (int j = 0; j < 5; ++j)
            *(float4*)&s[4 * j] = *(const float4*)(bp + 4 * j);   // ds_read_b128
#pragma unroll
        for (int dc = 0; dc < 3; ++dc)
#pragma unroll
            for (int ci = 0; ci < 3; ++ci) {
                const float* wp = &wk[((dr * 3 + dc) * 3 + ci) * 3];
#pragma unroll
                for (int i = 0; i < 4; ++i) {
                    const float x = s[3 * (i + dc) + ci + 1];
                    acc[i * 3 + 0] = fmaf(x, wp[0], acc[i * 3 + 0]);
                    acc[i * 3 + 1] = fmaf(x, wp[1], acc[i * 3 + 1]);
                    acc[i * 3 + 2] = fmaf(x, wp[2], acc[i * 3 + 2]);
                }
            }
    }

    // ---- epilogue: bias + pos_emb + permuted store ----
    const int hg  = h0 + r;
    const int wg0 = w0 + (g << 2);
    const int n   = (hg >> 2) * 128 + (wg0 >> 2);
    const float* pp = pos + (size_t)n * 48 + (hg & 3) * 12;   // 48B aligned
    const float4 p0 = ((const float4*)pp)[0];
    const float4 p1 = ((const float4*)pp)[1];
    const float4 p2 = ((const float4*)pp)[2];

    float v[12];
    v[0]  = acc[0]  + bs[0] + p0.x;  v[1]  = acc[1]  + bs[1] + p0.y;
    v[2]  = acc[2]  + bs[2] + p0.z;  v[3]  = acc[3]  + bs[0] + p0.w;
    v[4]  = acc[4]  + bs[1] + p1.x;  v[5]  = acc[5]  + bs[2] + p1.y;
    v[6]  = acc[6]  + bs[0] + p1.z;  v[7]  = acc[7]  + bs[1] + p1.w;
    v[8]  = acc[8]  + bs[2] + p2.x;  v[9]  = acc[9]  + bs[0] + p2.y;
    v[10] = acc[10] + bs[1] + p2.z;  v[11] = acc[11] + bs[2] + p2.w;

    const int np = (hg >> 4) * 32 + (wg0 >> 4);
    float* op = out + (size_t)b * 786432 + (size_t)np * 768
                    + (hg & 15) * 48 + ((wg0 >> 2) & 3) * 12;
    ((float4*)op)[0] = make_float4(v[0], v[1], v[2],  v[3]);
    ((float4*)op)[1] = make_float4(v[4], v[5], v[6],  v[7]);
    ((float4*)op)[2] = make_float4(v[8], v[9], v[10], v[11]);
}

extern "C" void kernel_launch(void* const* d_in, const int* in_sizes, int n_in,
                              void* d_out, int out_size, void* d_ws, size_t ws_size,
                              hipStream_t stream) {
    const float* X    = (const float*)d_in[0];
    const float* Kw   = (const float*)d_in[1];
    const float* bias = (const float*)d_in[2];
    const float* pos  = (const float*)d_in[3];
    float* out = (float*)d_out;

    dim3 grid(IMW / 64, IMH / 16, BATCH);   // 8 x 32 x 32 = 8192 blocks
    patch_enc_kernel<<<grid, 256, 0, stream>>>(X, Kw, bias, pos, out);
}